// Round 4
// baseline (154.897 us; speedup 1.0000x reference)
//
#include <hip/hip_runtime.h>
#include <math.h>

#define CEPS 1e-9f

typedef _Float16 half8 __attribute__((ext_vector_type(8)));
typedef _Float16 h2 __attribute__((ext_vector_type(2)));
typedef __fp16 fp16x2 __attribute__((ext_vector_type(2)));
typedef float floatx16 __attribute__((ext_vector_type(16)));

// x  : [4,56,56,8,32] fp32    W: [4,4,128,32] fp32    bias: [128] fp32
// out: [4,112,112,128] fp32 act
//
// R16: occupancy 5->6 waves/SIMD. History:
//  R12: 75us, (256,4), 124 unified regs, occ 38%, VALU 48% -> latency-bound.
//  R13: (256,6) + af-load CSE across K-halves -> spill, 326us.
//  R14: asm-laundered af addrs, (256,6): routing live ~90 > 85 cap -> small
//       spill, 94us.
//  R15: (256,5): spill-free (WRITE 30MB), 61.4us, VALU 65%, occ 41%.
//  R16: scx f16 [8][136] (8.7KB; LDS 33.3->16KB total) + va2 read directly
//       from LDS as f16 (kills 8 pkrtz + 16-VGPR vq transient -> routing
//       live ~74) -> (256,6) should now fit the 85-reg cap spill-free.
// Structure:
//  (a) xt/scx share one 16KB LDS buffer (xt dead after K-loop).
//  (b) K-loop in two 2-n-tile passes, acc=32 AGPR; votes pkrtz-packed to
//      32 h2 VGPRs (f16 round-trip exact).
//  (c) af LDS addresses laundered through empty asm per (half,s) +
//      sched_barrier between halves (R13 lesson: prevents cross-half CSE).
//  (d) nq / logit fdot2 chains split 4-way.
//  (e) scx stores f16 bits straight from pf; read back with 2x ds_read_b128
//      -> bit-identical va2, fewer instructions, fewer live regs.

template<int CTRL>
__device__ __forceinline__ float dpp_add(float v) {
    return v + __int_as_float(__builtin_amdgcn_update_dpp(
        0, __float_as_int(v), CTRL, 0xF, 0xF, false));
}
template<int CTRL>
__device__ __forceinline__ h2 dpp_add_h2(h2 v) {
    int t = __builtin_amdgcn_update_dpp(
        0, __builtin_bit_cast(int, v), CTRL, 0xF, 0xF, false);
    return v + __builtin_bit_cast(h2, t);
}
// sum over the 8-lane i-group (lane bits 0..2), both f16 components in parallel
__device__ __forceinline__ h2 sum_i8_h2(h2 v) {
    v = dpp_add_h2<0xB1>(v);     // quad_perm xor1
    v = dpp_add_h2<0x4E>(v);     // quad_perm xor2
    v = dpp_add_h2<0x141>(v);    // row_half_mirror (cross-quad)
    return v;
}
__device__ __forceinline__ h2 pkrtz(float a, float b) {
    return __builtin_bit_cast(h2, __builtin_amdgcn_cvt_pkrtz(a, b));
}
__device__ __forceinline__ float fdot2(h2 a, h2 b, float c) {
    return __builtin_amdgcn_fdot2(__builtin_bit_cast(fp16x2, a),
                                  __builtin_bit_cast(fp16x2, b), c, false);
}
__device__ __forceinline__ h2 hsel(bool c, h2 a, h2 b) {
    int r = c ? __builtin_bit_cast(int, a) : __builtin_bit_cast(int, b);
    return __builtin_bit_cast(h2, r);
}

// B[k][n] fragment table: idx = ((parity*8 + s)*4 + t)*64 + l -> 8 f16
__global__ __launch_bounds__(256) void prep_w(const float* __restrict__ Wt,
                                              _Float16* __restrict__ wb) {
    int idx = blockIdx.x * 256 + threadIdx.x;    // [0, 8192)
    int parity = idx >> 11;
    int s = (idx >> 8) & 7;
    int t = (idx >> 6) & 3;
    int l = idx & 63;
    int rh = parity >> 1, rw = parity & 1;
    int n = t * 32 + (l & 31);
    int h = l >> 5;
    int ci0 = ((s & 1) << 4) + (h << 3);
    int kh = ((s >> 2) << 1) + 1 - rh;
    int kw = (((s >> 1) & 1) << 1) + 1 - rw;
    const float* src = Wt + (((kh * 4 + kw) * 128 + n) << 5) + ci0;
    float4 w0 = *(const float4*)src;
    float4 w1 = *(const float4*)(src + 4);
    half8 hv;
    hv[0] = (_Float16)w0.x; hv[1] = (_Float16)w0.y;
    hv[2] = (_Float16)w0.z; hv[3] = (_Float16)w0.w;
    hv[4] = (_Float16)w1.x; hv[5] = (_Float16)w1.y;
    hv[6] = (_Float16)w1.z; hv[7] = (_Float16)w1.w;
    *(half8*)(wb + ((long)idx << 3)) = hv;
}

__global__ __launch_bounds__(256, 6) void caps_mfma(
    const float* __restrict__ x,
    const _Float16* __restrict__ wb,
    const float* __restrict__ bias,
    float* __restrict__ out)
{
    // Shared buffer, two lifetimes:
    //  phase 1 (stage + K-loop): xt = [cell(5x5)][i(8)][ci padded 32->40] f16, 16000 B
    //  phase 2 (routing): scxh = [wave(4)][i(8)][ca padded 128->136] f16, 8704 B
    __shared__ __align__(16) unsigned char smem[16000];
    _Float16* xt = (_Float16*)smem;
    _Float16* scxh = (_Float16*)smem;

    const int tid = threadIdx.x;
    const int tile = blockIdx.x;            // 0..195 : 14x14 tiles of 4x4 pixels
    const int tu = tile / 14, tv = tile - tu * 14;
    const int u0 = tu * 4, v0 = tv * 4;
    const int rh = blockIdx.y >> 1;         // p & 1
    const int rw = blockIdx.y & 1;          // q & 1
    const int bp = blockIdx.z;              // b'
    const _Float16* wsrc = wb + ((long)blockIdx.y << 14);   // parity slice, 16 KB

    // ---- stage x: fp32 -> f16 tile [ri(5)][rj(5)][i(8)][ci], zero-filled OOB ----
    #pragma unroll
    for (int it = 0; it < 4; ++it) {
        int idx = tid + (it << 8);
        if (idx < 800) {
            int cell = idx >> 5;            // 0..24
            int r = idx & 31;
            int i = r >> 2;
            int ci0 = (r & 3) << 3;
            int ri = cell / 5, rj = cell - ri * 5;
            int gi = u0 + rh - 1 + ri;
            int gj = v0 + rw - 1 + rj;
            float tmp[8] = {0.f, 0.f, 0.f, 0.f, 0.f, 0.f, 0.f, 0.f};
            if ((unsigned)gi < 56u && (unsigned)gj < 56u) {
                const float* src = x + (((i & 3) * 56 + gi) * 56 + gj) * 256
                                     + ((bp * 2 + (i >> 2)) << 5) + ci0;
                float4 a0 = *(const float4*)src;
                float4 a1 = *(const float4*)(src + 4);
                tmp[0] = a0.x; tmp[1] = a0.y; tmp[2] = a0.z; tmp[3] = a0.w;
                tmp[4] = a1.x; tmp[5] = a1.y; tmp[6] = a1.z; tmp[7] = a1.w;
            }
            half8 hv;
            #pragma unroll
            for (int j = 0; j < 8; ++j) hv[j] = (_Float16)tmp[j];
            *(half8*)(xt + (cell * 8 + i) * 40 + ci0) = hv;
        }
    }
    __syncthreads();

    const int l = tid & 63;
    const int w = tid >> 6;                 // wave = u-row within tile
    const int col = l & 31, h = l >> 5;
    const int invA = (l & 31) * 40 + (h << 3);

    // ---- MFMA K-loop, TWO passes of 2 n-tiles: acc is 32 AGPR (not 64). ----
    // After each pass, pack f32 acc -> f16 pairs along j (= pixl*4+il):
    // pf[t][m] = (votes[j=2m], votes[j=2m+1]) at ca = 32t+col.
    h2 pf[4][8];
    #pragma unroll
    for (int half = 0; half < 2; ++half) {
        floatx16 acc0, acc1;
        #pragma unroll
        for (int j = 0; j < 16; ++j) { acc0[j] = 0.f; acc1[j] = 0.f; }
        const int tb = half << 1;
        #pragma unroll
        for (int s = 0; s < 8; ++s) {
            const int tkh = s >> 2;
            const int tkw = (s >> 1) & 1;
            const int row = w + 1 - tkh;
            int aoff = (row * 5 + 1 - tkw) * 320 + ((s & 1) << 4) + invA;
            // SPILL FIX (R14): make the A-frag address opaque so the
            // compiler cannot CSE/hoist the 8 identical xt loads across the
            // two halves (R13: that hoisting (+32 VGPR) caused the spill).
            asm("" : "+v"(aoff));
            half8 af = *(const half8*)(xt + aoff);
            half8 bf0 = *(const half8*)(wsrc + (((s * 4 + tb) * 64 + l) << 3));
            half8 bf1 = *(const half8*)(wsrc + (((s * 4 + tb + 1) * 64 + l) << 3));
            acc0 = __builtin_amdgcn_mfma_f32_32x32x16_f16(af, bf0, acc0, 0, 0, 0);
            acc1 = __builtin_amdgcn_mfma_f32_32x32x16_f16(af, bf1, acc1, 0, 0, 0);
        }
        #pragma unroll
        for (int m = 0; m < 8; ++m) {
            pf[tb][m]     = pkrtz(acc0[2 * m], acc0[2 * m + 1]);
            pf[tb + 1][m] = pkrtz(acc1[2 * m], acc1[2 * m + 1]);
        }
        // keep half-2's loads from being software-pipelined into half-1
        // (would extend acc/af liveness across the packing)
        __builtin_amdgcn_sched_barrier(0);
    }

    // xt is dead; scxh aliases it. All waves must pass here before writing.
    __syncthreads();

    // ---- routing: lane = (c = l>>3, i = l&7); a(16) in-register as h2[8] ----
    _Float16* scb = scxh + w * (8 * 136);   // wave-local after the barrier
    const int cI = l >> 3;
    const int iI = l & 7;

    // bias as packed f16 pairs, loaded once (8 distinct addrs/wave -> L1)
    h2 bq2[8];
    {
        const float* bpt = bias + (cI << 4);
        float4 b0 = *(const float4*)bpt;
        float4 b1 = *(const float4*)(bpt + 4);
        float4 b2 = *(const float4*)(bpt + 8);
        float4 b3 = *(const float4*)(bpt + 12);
        bq2[0] = pkrtz(b0.x, b0.y); bq2[1] = pkrtz(b0.z, b0.w);
        bq2[2] = pkrtz(b1.x, b1.y); bq2[3] = pkrtz(b1.z, b1.w);
        bq2[4] = pkrtz(b2.x, b2.y); bq2[5] = pkrtz(b2.z, b2.w);
        bq2[6] = pkrtz(b3.x, b3.y); bq2[7] = pkrtz(b3.z, b3.w);
    }
    const h2 c0125 = pkrtz(0.125f, 0.125f);

    #pragma unroll
    for (int pixl = 0; pixl < 4; ++pixl) {
        // transpose: packed f16 votes -> scxh[i][ca] (row stride 136); i = 4h+il
        // (same f16 bits as the old f32 round-trip -> numerics identical)
        #pragma unroll
        for (int t = 0; t < 4; ++t)
            #pragma unroll
            for (int il = 0; il < 4; ++il) {
                h2 pp = pf[t][(pixl << 1) + (il >> 1)];
                _Float16 v = (il & 1) ? pp.y : pp.x;
                scb[((h << 2) + il) * 136 + t * 32 + col] = v;
            }

        // read my (c,i) row: 2x ds_read_b128 -> va2 directly (no cvt/pkrtz)
        const _Float16* rbh = scb + iI * 136 + (cI << 4);
        h2 va2[8];
        *(half8*)&va2[0] = *(const half8*)(rbh);
        *(half8*)&va2[4] = *(const half8*)(rbh + 8);

        h2 pre2[8];
        float lg;

        // ---- round 0: route = 1/8 ----
        #pragma unroll
        for (int j = 0; j < 8; ++j) {
            h2 s2 = sum_i8_h2(va2[j]);
            pre2[j] = s2 * c0125 + bq2[j];           // v_pk_fma_f16
        }
        {
            float n0 = fdot2(pre2[0], pre2[0], 0.f);
            float n1 = fdot2(pre2[1], pre2[1], 0.f);
            float n2 = fdot2(pre2[2], pre2[2], 0.f);
            float n3 = fdot2(pre2[3], pre2[3], 0.f);
            n0 = fdot2(pre2[4], pre2[4], n0);
            n1 = fdot2(pre2[5], pre2[5], n1);
            n2 = fdot2(pre2[6], pre2[6], n2);
            n3 = fdot2(pre2[7], pre2[7], n3);
            float nq = (n0 + n1) + (n2 + n3);
            float sc = nq * __builtin_amdgcn_rcpf(1.f + nq)
                          * __builtin_amdgcn_rsqf(nq + CEPS);
            h2 sc2 = pkrtz(sc, sc);
            #pragma unroll
            for (int j = 0; j < 8; ++j) pre2[j] *= sc2;   // pre2 = act
            float d0 = fdot2(va2[0], pre2[0], 0.f);
            float d1 = fdot2(va2[1], pre2[1], 0.f);
            float d2 = fdot2(va2[2], pre2[2], 0.f);
            float d3 = fdot2(va2[3], pre2[3], 0.f);
            d0 = fdot2(va2[4], pre2[4], d0);
            d1 = fdot2(va2[5], pre2[5], d1);
            d2 = fdot2(va2[6], pre2[6], d2);
            d3 = fdot2(va2[7], pre2[7], d3);
            lg = (d0 + d1) + (d2 + d3);               // per-(i,c), fp32
        }

        // ---- rounds 1,2 ----
        #pragma unroll
        for (int r = 1; r < 3; ++r) {
            // softmax over c (lane bits 3..5); logits bounded, no max-sub; fp32
            float e = __expf(lg);
            float ss = dpp_add<0x128>(e);             // ror8 == xor8 (in-row)
            ss += __int_as_float(__builtin_amdgcn_ds_swizzle(
                      __float_as_int(ss), 0x401F));   // xor16
            ss += __shfl_xor(ss, 32);
            float route = e * __builtin_amdgcn_rcpf(ss);
            h2 rt2 = pkrtz(route, route);
            #pragma unroll
            for (int j = 0; j < 8; ++j) {
                h2 p = sum_i8_h2(rt2 * va2[j]);       // pk_mul + packed i-sum
                pre2[j] = p + bq2[j];                 // v_pk_add_f16
            }
            float n0 = fdot2(pre2[0], pre2[0], 0.f);
            float n1 = fdot2(pre2[1], pre2[1], 0.f);
            float n2 = fdot2(pre2[2], pre2[2], 0.f);
            float n3 = fdot2(pre2[3], pre2[3], 0.f);
            n0 = fdot2(pre2[4], pre2[4], n0);
            n1 = fdot2(pre2[5], pre2[5], n1);
            n2 = fdot2(pre2[6], pre2[6], n2);
            n3 = fdot2(pre2[7], pre2[7], n3);
            float nq = (n0 + n1) + (n2 + n3);
            float sc = nq * __builtin_amdgcn_rcpf(1.f + nq)
                          * __builtin_amdgcn_rsqf(nq + CEPS);
            h2 sc2 = pkrtz(sc, sc);
            #pragma unroll
            for (int j = 0; j < 8; ++j) pre2[j] *= sc2;   // act
            if (r < 2) {
                float d0 = fdot2(va2[0], pre2[0], lg);
                float d1 = fdot2(va2[1], pre2[1], 0.f);
                float d2 = fdot2(va2[2], pre2[2], 0.f);
                float d3 = fdot2(va2[3], pre2[3], 0.f);
                d0 = fdot2(va2[4], pre2[4], d0);
                d1 = fdot2(va2[5], pre2[5], d1);
                d2 = fdot2(va2[6], pre2[6], d2);
                d3 = fdot2(va2[7], pre2[7], d3);
                lg = (d0 + d1) + (d2 + d3);
            }
        }

        // ---- store: lanes i<4 each write one float4 quad -> fully coalesced ----
        if (iI < 4) {
            // quad q=iI covers pairs j0=2(iI&1)+4((iI>>1)&1), j0+1
            h2 h0 = hsel((iI & 2) != 0, pre2[4], pre2[0]);
            h2 h1 = hsel((iI & 2) != 0, pre2[5], pre2[1]);
            h2 h2_ = hsel((iI & 2) != 0, pre2[6], pre2[2]);
            h2 h3 = hsel((iI & 2) != 0, pre2[7], pre2[3]);
            h2 p0 = hsel((iI & 1) != 0, h2_, h0);
            h2 p1 = hsel((iI & 1) != 0, h3, h1);
            float4 o4 = make_float4((float)p0.x, (float)p0.y,
                                    (float)p1.x, (float)p1.y);
            const int p = ((u0 + w) << 1) + rh;
            const int q = ((v0 + pixl) << 1) + rw;
            *(float4*)(out + (((bp * 112 + p) * 112 + q) << 7) + cI * 16 + iI * 4) = o4;
        }
    }
}

extern "C" void kernel_launch(void* const* d_in, const int* in_sizes, int n_in,
                              void* d_out, int out_size, void* d_ws, size_t ws_size,
                              hipStream_t stream) {
    const float* x  = (const float*)d_in[0];
    const float* Wt = (const float*)d_in[1];
    const float* b  = (const float*)d_in[2];
    float* out = (float*)d_out;
    _Float16* wb = (_Float16*)d_ws;          // 4 parities x 16384 f16 = 64 KB

    prep_w<<<32, 256, 0, stream>>>(Wt, wb);
    dim3 grid(196, 4, 4);    // 14x14 4x4-pixel tiles, 4 parity classes, 4 b'
    caps_mfma<<<grid, 256, 0, stream>>>(x, wb, b, out);
}

// Round 5
// 120.123 us; speedup vs baseline: 1.2895x; 1.2895x over previous
//
#include <hip/hip_runtime.h>
#include <math.h>

#define CEPS 1e-9f

typedef _Float16 half8 __attribute__((ext_vector_type(8)));
typedef _Float16 h2 __attribute__((ext_vector_type(2)));
typedef __fp16 fp16x2 __attribute__((ext_vector_type(2)));
typedef float floatx16 __attribute__((ext_vector_type(16)));

// x  : [4,56,56,8,32] fp32    W: [4,4,128,32] fp32    bias: [128] fp32
// out: [4,112,112,128] fp32 act
//
// R17: R16's trims at the proven spill-free (256,5) cap. History:
//  R12: 75us, (256,4), 124 unified regs, occ 38%, VALU 48% -> latency-bound.
//  R13: (256,6) + af-load CSE across K-halves -> spill, 326us.
//  R14: asm-laundered af addrs, (256,6): still spills, 94us.
//  R15: (256,5): spill-free (WRITE 30MB), 61.4us, VALU 65%, occ 41%.
//  R16: scx->f16 + direct f16 va2 reads, but (256,6) AGAIN spilled
//       (WRITE 194MB, 98.8us, VGPR_Count=40: allocator refuses to pack).
//  R17: same trims, (256,5). LDS 16KB; routing ~100 fewer VALU/lane.
// Structure:
//  (a) xt/scx share one 16KB LDS buffer (xt dead after K-loop).
//  (b) K-loop in two 2-n-tile passes, acc=32 AGPR; votes pkrtz-packed to
//      32 h2 VGPRs (f16 round-trip exact).
//  (c) af LDS addresses laundered through empty asm per (half,s) +
//      sched_barrier between halves (R13 lesson: prevents cross-half CSE).
//  (d) nq / logit fdot2 chains split 4-way.
//  (e) scx stores f16 bits straight from pf; read back with 2x ds_read_b128
//      -> bit-identical va2, fewer instructions, fewer live regs.
// LDS conflicts (1.1M cyc = ~0.5us/SIMD-equivalent) measured negligible.

template<int CTRL>
__device__ __forceinline__ float dpp_add(float v) {
    return v + __int_as_float(__builtin_amdgcn_update_dpp(
        0, __float_as_int(v), CTRL, 0xF, 0xF, false));
}
template<int CTRL>
__device__ __forceinline__ h2 dpp_add_h2(h2 v) {
    int t = __builtin_amdgcn_update_dpp(
        0, __builtin_bit_cast(int, v), CTRL, 0xF, 0xF, false);
    return v + __builtin_bit_cast(h2, t);
}
// sum over the 8-lane i-group (lane bits 0..2), both f16 components in parallel
__device__ __forceinline__ h2 sum_i8_h2(h2 v) {
    v = dpp_add_h2<0xB1>(v);     // quad_perm xor1
    v = dpp_add_h2<0x4E>(v);     // quad_perm xor2
    v = dpp_add_h2<0x141>(v);    // row_half_mirror (cross-quad)
    return v;
}
__device__ __forceinline__ h2 pkrtz(float a, float b) {
    return __builtin_bit_cast(h2, __builtin_amdgcn_cvt_pkrtz(a, b));
}
__device__ __forceinline__ float fdot2(h2 a, h2 b, float c) {
    return __builtin_amdgcn_fdot2(__builtin_bit_cast(fp16x2, a),
                                  __builtin_bit_cast(fp16x2, b), c, false);
}
__device__ __forceinline__ h2 hsel(bool c, h2 a, h2 b) {
    int r = c ? __builtin_bit_cast(int, a) : __builtin_bit_cast(int, b);
    return __builtin_bit_cast(h2, r);
}

// B[k][n] fragment table: idx = ((parity*8 + s)*4 + t)*64 + l -> 8 f16
__global__ __launch_bounds__(256) void prep_w(const float* __restrict__ Wt,
                                              _Float16* __restrict__ wb) {
    int idx = blockIdx.x * 256 + threadIdx.x;    // [0, 8192)
    int parity = idx >> 11;
    int s = (idx >> 8) & 7;
    int t = (idx >> 6) & 3;
    int l = idx & 63;
    int rh = parity >> 1, rw = parity & 1;
    int n = t * 32 + (l & 31);
    int h = l >> 5;
    int ci0 = ((s & 1) << 4) + (h << 3);
    int kh = ((s >> 2) << 1) + 1 - rh;
    int kw = (((s >> 1) & 1) << 1) + 1 - rw;
    const float* src = Wt + (((kh * 4 + kw) * 128 + n) << 5) + ci0;
    float4 w0 = *(const float4*)src;
    float4 w1 = *(const float4*)(src + 4);
    half8 hv;
    hv[0] = (_Float16)w0.x; hv[1] = (_Float16)w0.y;
    hv[2] = (_Float16)w0.z; hv[3] = (_Float16)w0.w;
    hv[4] = (_Float16)w1.x; hv[5] = (_Float16)w1.y;
    hv[6] = (_Float16)w1.z; hv[7] = (_Float16)w1.w;
    *(half8*)(wb + ((long)idx << 3)) = hv;
}

__global__ __launch_bounds__(256, 5) void caps_mfma(
    const float* __restrict__ x,
    const _Float16* __restrict__ wb,
    const float* __restrict__ bias,
    float* __restrict__ out)
{
    // Shared buffer, two lifetimes:
    //  phase 1 (stage + K-loop): xt = [cell(5x5)][i(8)][ci padded 32->40] f16, 16000 B
    //  phase 2 (routing): scxh = [wave(4)][i(8)][ca padded 128->136] f16, 8704 B
    __shared__ __align__(16) unsigned char smem[16000];
    _Float16* xt = (_Float16*)smem;
    _Float16* scxh = (_Float16*)smem;

    const int tid = threadIdx.x;
    const int tile = blockIdx.x;            // 0..195 : 14x14 tiles of 4x4 pixels
    const int tu = tile / 14, tv = tile - tu * 14;
    const int u0 = tu * 4, v0 = tv * 4;
    const int rh = blockIdx.y >> 1;         // p & 1
    const int rw = blockIdx.y & 1;          // q & 1
    const int bp = blockIdx.z;              // b'
    const _Float16* wsrc = wb + ((long)blockIdx.y << 14);   // parity slice, 16 KB

    // ---- stage x: fp32 -> f16 tile [ri(5)][rj(5)][i(8)][ci], zero-filled OOB ----
    #pragma unroll
    for (int it = 0; it < 4; ++it) {
        int idx = tid + (it << 8);
        if (idx < 800) {
            int cell = idx >> 5;            // 0..24
            int r = idx & 31;
            int i = r >> 2;
            int ci0 = (r & 3) << 3;
            int ri = cell / 5, rj = cell - ri * 5;
            int gi = u0 + rh - 1 + ri;
            int gj = v0 + rw - 1 + rj;
            float tmp[8] = {0.f, 0.f, 0.f, 0.f, 0.f, 0.f, 0.f, 0.f};
            if ((unsigned)gi < 56u && (unsigned)gj < 56u) {
                const float* src = x + (((i & 3) * 56 + gi) * 56 + gj) * 256
                                     + ((bp * 2 + (i >> 2)) << 5) + ci0;
                float4 a0 = *(const float4*)src;
                float4 a1 = *(const float4*)(src + 4);
                tmp[0] = a0.x; tmp[1] = a0.y; tmp[2] = a0.z; tmp[3] = a0.w;
                tmp[4] = a1.x; tmp[5] = a1.y; tmp[6] = a1.z; tmp[7] = a1.w;
            }
            half8 hv;
            #pragma unroll
            for (int j = 0; j < 8; ++j) hv[j] = (_Float16)tmp[j];
            *(half8*)(xt + (cell * 8 + i) * 40 + ci0) = hv;
        }
    }
    __syncthreads();

    const int l = tid & 63;
    const int w = tid >> 6;                 // wave = u-row within tile
    const int col = l & 31, h = l >> 5;
    const int invA = (l & 31) * 40 + (h << 3);

    // ---- MFMA K-loop, TWO passes of 2 n-tiles: acc is 32 AGPR (not 64). ----
    // After each pass, pack f32 acc -> f16 pairs along j (= pixl*4+il):
    // pf[t][m] = (votes[j=2m], votes[j=2m+1]) at ca = 32t+col.
    h2 pf[4][8];
    #pragma unroll
    for (int half = 0; half < 2; ++half) {
        floatx16 acc0, acc1;
        #pragma unroll
        for (int j = 0; j < 16; ++j) { acc0[j] = 0.f; acc1[j] = 0.f; }
        const int tb = half << 1;
        #pragma unroll
        for (int s = 0; s < 8; ++s) {
            const int tkh = s >> 2;
            const int tkw = (s >> 1) & 1;
            const int row = w + 1 - tkh;
            int aoff = (row * 5 + 1 - tkw) * 320 + ((s & 1) << 4) + invA;
            // SPILL FIX (R14): make the A-frag address opaque so the
            // compiler cannot CSE/hoist the 8 identical xt loads across the
            // two halves (R13: that hoisting (+32 VGPR) caused the spill).
            asm("" : "+v"(aoff));
            half8 af = *(const half8*)(xt + aoff);
            half8 bf0 = *(const half8*)(wsrc + (((s * 4 + tb) * 64 + l) << 3));
            half8 bf1 = *(const half8*)(wsrc + (((s * 4 + tb + 1) * 64 + l) << 3));
            acc0 = __builtin_amdgcn_mfma_f32_32x32x16_f16(af, bf0, acc0, 0, 0, 0);
            acc1 = __builtin_amdgcn_mfma_f32_32x32x16_f16(af, bf1, acc1, 0, 0, 0);
        }
        #pragma unroll
        for (int m = 0; m < 8; ++m) {
            pf[tb][m]     = pkrtz(acc0[2 * m], acc0[2 * m + 1]);
            pf[tb + 1][m] = pkrtz(acc1[2 * m], acc1[2 * m + 1]);
        }
        // keep half-2's loads from being software-pipelined into half-1
        // (would extend acc/af liveness across the packing)
        __builtin_amdgcn_sched_barrier(0);
    }

    // xt is dead; scxh aliases it. All waves must pass here before writing.
    __syncthreads();

    // ---- routing: lane = (c = l>>3, i = l&7); a(16) in-register as h2[8] ----
    _Float16* scb = scxh + w * (8 * 136);   // wave-local after the barrier
    const int cI = l >> 3;
    const int iI = l & 7;

    // bias as packed f16 pairs, loaded once (8 distinct addrs/wave -> L1)
    h2 bq2[8];
    {
        const float* bpt = bias + (cI << 4);
        float4 b0 = *(const float4*)bpt;
        float4 b1 = *(const float4*)(bpt + 4);
        float4 b2 = *(const float4*)(bpt + 8);
        float4 b3 = *(const float4*)(bpt + 12);
        bq2[0] = pkrtz(b0.x, b0.y); bq2[1] = pkrtz(b0.z, b0.w);
        bq2[2] = pkrtz(b1.x, b1.y); bq2[3] = pkrtz(b1.z, b1.w);
        bq2[4] = pkrtz(b2.x, b2.y); bq2[5] = pkrtz(b2.z, b2.w);
        bq2[6] = pkrtz(b3.x, b3.y); bq2[7] = pkrtz(b3.z, b3.w);
    }
    const h2 c0125 = pkrtz(0.125f, 0.125f);

    #pragma unroll
    for (int pixl = 0; pixl < 4; ++pixl) {
        // transpose: packed f16 votes -> scxh[i][ca] (row stride 136); i = 4h+il
        // (same f16 bits as the old f32 round-trip -> numerics identical)
        #pragma unroll
        for (int t = 0; t < 4; ++t)
            #pragma unroll
            for (int il = 0; il < 4; ++il) {
                h2 pp = pf[t][(pixl << 1) + (il >> 1)];
                _Float16 v = (il & 1) ? pp.y : pp.x;
                scb[((h << 2) + il) * 136 + t * 32 + col] = v;
            }

        // read my (c,i) row: 2x ds_read_b128 -> va2 directly (no cvt/pkrtz)
        const _Float16* rbh = scb + iI * 136 + (cI << 4);
        h2 va2[8];
        *(half8*)&va2[0] = *(const half8*)(rbh);
        *(half8*)&va2[4] = *(const half8*)(rbh + 8);

        h2 pre2[8];
        float lg;

        // ---- round 0: route = 1/8 ----
        #pragma unroll
        for (int j = 0; j < 8; ++j) {
            h2 s2 = sum_i8_h2(va2[j]);
            pre2[j] = s2 * c0125 + bq2[j];           // v_pk_fma_f16
        }
        {
            float n0 = fdot2(pre2[0], pre2[0], 0.f);
            float n1 = fdot2(pre2[1], pre2[1], 0.f);
            float n2 = fdot2(pre2[2], pre2[2], 0.f);
            float n3 = fdot2(pre2[3], pre2[3], 0.f);
            n0 = fdot2(pre2[4], pre2[4], n0);
            n1 = fdot2(pre2[5], pre2[5], n1);
            n2 = fdot2(pre2[6], pre2[6], n2);
            n3 = fdot2(pre2[7], pre2[7], n3);
            float nq = (n0 + n1) + (n2 + n3);
            float sc = nq * __builtin_amdgcn_rcpf(1.f + nq)
                          * __builtin_amdgcn_rsqf(nq + CEPS);
            h2 sc2 = pkrtz(sc, sc);
            #pragma unroll
            for (int j = 0; j < 8; ++j) pre2[j] *= sc2;   // pre2 = act
            float d0 = fdot2(va2[0], pre2[0], 0.f);
            float d1 = fdot2(va2[1], pre2[1], 0.f);
            float d2 = fdot2(va2[2], pre2[2], 0.f);
            float d3 = fdot2(va2[3], pre2[3], 0.f);
            d0 = fdot2(va2[4], pre2[4], d0);
            d1 = fdot2(va2[5], pre2[5], d1);
            d2 = fdot2(va2[6], pre2[6], d2);
            d3 = fdot2(va2[7], pre2[7], d3);
            lg = (d0 + d1) + (d2 + d3);               // per-(i,c), fp32
        }

        // ---- rounds 1,2 ----
        #pragma unroll
        for (int r = 1; r < 3; ++r) {
            // softmax over c (lane bits 3..5); logits bounded, no max-sub; fp32
            float e = __expf(lg);
            float ss = dpp_add<0x128>(e);             // ror8 == xor8 (in-row)
            ss += __int_as_float(__builtin_amdgcn_ds_swizzle(
                      __float_as_int(ss), 0x401F));   // xor16
            ss += __shfl_xor(ss, 32);
            float route = e * __builtin_amdgcn_rcpf(ss);
            h2 rt2 = pkrtz(route, route);
            #pragma unroll
            for (int j = 0; j < 8; ++j) {
                h2 p = sum_i8_h2(rt2 * va2[j]);       // pk_mul + packed i-sum
                pre2[j] = p + bq2[j];                 // v_pk_add_f16
            }
            float n0 = fdot2(pre2[0], pre2[0], 0.f);
            float n1 = fdot2(pre2[1], pre2[1], 0.f);
            float n2 = fdot2(pre2[2], pre2[2], 0.f);
            float n3 = fdot2(pre2[3], pre2[3], 0.f);
            n0 = fdot2(pre2[4], pre2[4], n0);
            n1 = fdot2(pre2[5], pre2[5], n1);
            n2 = fdot2(pre2[6], pre2[6], n2);
            n3 = fdot2(pre2[7], pre2[7], n3);
            float nq = (n0 + n1) + (n2 + n3);
            float sc = nq * __builtin_amdgcn_rcpf(1.f + nq)
                          * __builtin_amdgcn_rsqf(nq + CEPS);
            h2 sc2 = pkrtz(sc, sc);
            #pragma unroll
            for (int j = 0; j < 8; ++j) pre2[j] *= sc2;   // act
            if (r < 2) {
                float d0 = fdot2(va2[0], pre2[0], lg);
                float d1 = fdot2(va2[1], pre2[1], 0.f);
                float d2 = fdot2(va2[2], pre2[2], 0.f);
                float d3 = fdot2(va2[3], pre2[3], 0.f);
                d0 = fdot2(va2[4], pre2[4], d0);
                d1 = fdot2(va2[5], pre2[5], d1);
                d2 = fdot2(va2[6], pre2[6], d2);
                d3 = fdot2(va2[7], pre2[7], d3);
                lg = (d0 + d1) + (d2 + d3);
            }
        }

        // ---- store: lanes i<4 each write one float4 quad -> fully coalesced ----
        if (iI < 4) {
            // quad q=iI covers pairs j0=2(iI&1)+4((iI>>1)&1), j0+1
            h2 h0 = hsel((iI & 2) != 0, pre2[4], pre2[0]);
            h2 h1 = hsel((iI & 2) != 0, pre2[5], pre2[1]);
            h2 h2_ = hsel((iI & 2) != 0, pre2[6], pre2[2]);
            h2 h3 = hsel((iI & 2) != 0, pre2[7], pre2[3]);
            h2 p0 = hsel((iI & 1) != 0, h2_, h0);
            h2 p1 = hsel((iI & 1) != 0, h3, h1);
            float4 o4 = make_float4((float)p0.x, (float)p0.y,
                                    (float)p1.x, (float)p1.y);
            const int p = ((u0 + w) << 1) + rh;
            const int q = ((v0 + pixl) << 1) + rw;
            *(float4*)(out + (((bp * 112 + p) * 112 + q) << 7) + cI * 16 + iI * 4) = o4;
        }
    }
}

extern "C" void kernel_launch(void* const* d_in, const int* in_sizes, int n_in,
                              void* d_out, int out_size, void* d_ws, size_t ws_size,
                              hipStream_t stream) {
    const float* x  = (const float*)d_in[0];
    const float* Wt = (const float*)d_in[1];
    const float* b  = (const float*)d_in[2];
    float* out = (float*)d_out;
    _Float16* wb = (_Float16*)d_ws;          // 4 parities x 16384 f16 = 64 KB

    prep_w<<<32, 256, 0, stream>>>(Wt, wb);
    dim3 grid(196, 4, 4);    // 14x14 4x4-pixel tiles, 4 parity classes, 4 b'
    caps_mfma<<<grid, 256, 0, stream>>>(x, wb, b, out);
}

// Round 6
// 119.330 us; speedup vs baseline: 1.2981x; 1.0066x over previous
//
#include <hip/hip_runtime.h>
#include <math.h>

#define CEPS 1e-9f

typedef _Float16 half8 __attribute__((ext_vector_type(8)));
typedef _Float16 h2 __attribute__((ext_vector_type(2)));
typedef __fp16 fp16x2 __attribute__((ext_vector_type(2)));
typedef float floatx16 __attribute__((ext_vector_type(16)));

// x  : [4,56,56,8,32] fp32    W: [4,4,128,32] fp32    bias: [128] fp32
// out: [4,112,112,128] fp32 act
//
// R18: ILP-2 routing (jam two pixels). History:
//  R12: 75us, (256,4), occ 38%, VALU 48% -> latency-bound.
//  R13/R14/R16: every (256,6) attempt spilled (WRITE 194-789MB). Abandoned.
//  R15: (256,5) spill-free: 61.4us profiled.
//  R17: + f16 scx + direct f16 va2 reads: spill gate clean (WRITE=25MB=out),
//       VALU busy-time 40->37us, but ~30us of exposed latency remains
//       (VALU 52-65%, occ ~43%). Serial chains per pixl pass: LDS round-trip,
//       softmax exp->dpp->ds_swizzle->bpermute (~130cy), norm->rcp/rsq chain.
//  R18: routing processes pixl pairs {0,2} then {1,3} as two independent
//       register streams in one straight-line block -> 2x in-wave ILP on all
//       serial chains, half the exposed LDS round-trips. Instruction count
//       and numerics identical to R17. Peak live ~76 arch regs < 102 cap.
// Structure:
//  (a) xt/scx share one 16KB LDS buffer (xt dead after K-loop).
//  (b) K-loop in two 2-n-tile passes, acc=32 AGPR; votes pkrtz-packed to
//      32 h2 VGPRs. pf frees half after each pair-group's transpose.
//  (c) af LDS addresses laundered through empty asm per (half,s) +
//      sched_barrier between halves (R13 lesson: prevents cross-half CSE).
//  (d) nq / logit fdot2 chains split 4-way per stream (8-way ILP jammed).
//  (e) scx stores f16 bits straight from pf; read back with 2x ds_read_b128.
//      Streams A/B reuse the same LDS rows: per-wave in-order DS makes the
//      write-B-after-read-A WAR safe without a barrier.
// SQ_LDS_BANK_CONFLICT is bit-identical across all rounds (stale counter) --
// do not use it as evidence either way.

template<int CTRL>
__device__ __forceinline__ float dpp_add(float v) {
    return v + __int_as_float(__builtin_amdgcn_update_dpp(
        0, __float_as_int(v), CTRL, 0xF, 0xF, false));
}
template<int CTRL>
__device__ __forceinline__ h2 dpp_add_h2(h2 v) {
    int t = __builtin_amdgcn_update_dpp(
        0, __builtin_bit_cast(int, v), CTRL, 0xF, 0xF, false);
    return v + __builtin_bit_cast(h2, t);
}
// sum over the 8-lane i-group (lane bits 0..2), both f16 components in parallel
__device__ __forceinline__ h2 sum_i8_h2(h2 v) {
    v = dpp_add_h2<0xB1>(v);     // quad_perm xor1
    v = dpp_add_h2<0x4E>(v);     // quad_perm xor2
    v = dpp_add_h2<0x141>(v);    // row_half_mirror (cross-quad)
    return v;
}
__device__ __forceinline__ h2 pkrtz(float a, float b) {
    return __builtin_bit_cast(h2, __builtin_amdgcn_cvt_pkrtz(a, b));
}
__device__ __forceinline__ float fdot2(h2 a, h2 b, float c) {
    return __builtin_amdgcn_fdot2(__builtin_bit_cast(fp16x2, a),
                                  __builtin_bit_cast(fp16x2, b), c, false);
}
__device__ __forceinline__ h2 hsel(bool c, h2 a, h2 b) {
    int r = c ? __builtin_bit_cast(int, a) : __builtin_bit_cast(int, b);
    return __builtin_bit_cast(h2, r);
}

// B[k][n] fragment table: idx = ((parity*8 + s)*4 + t)*64 + l -> 8 f16
__global__ __launch_bounds__(256) void prep_w(const float* __restrict__ Wt,
                                              _Float16* __restrict__ wb) {
    int idx = blockIdx.x * 256 + threadIdx.x;    // [0, 8192)
    int parity = idx >> 11;
    int s = (idx >> 8) & 7;
    int t = (idx >> 6) & 3;
    int l = idx & 63;
    int rh = parity >> 1, rw = parity & 1;
    int n = t * 32 + (l & 31);
    int h = l >> 5;
    int ci0 = ((s & 1) << 4) + (h << 3);
    int kh = ((s >> 2) << 1) + 1 - rh;
    int kw = (((s >> 1) & 1) << 1) + 1 - rw;
    const float* src = Wt + (((kh * 4 + kw) * 128 + n) << 5) + ci0;
    float4 w0 = *(const float4*)src;
    float4 w1 = *(const float4*)(src + 4);
    half8 hv;
    hv[0] = (_Float16)w0.x; hv[1] = (_Float16)w0.y;
    hv[2] = (_Float16)w0.z; hv[3] = (_Float16)w0.w;
    hv[4] = (_Float16)w1.x; hv[5] = (_Float16)w1.y;
    hv[6] = (_Float16)w1.z; hv[7] = (_Float16)w1.w;
    *(half8*)(wb + ((long)idx << 3)) = hv;
}

__global__ __launch_bounds__(256, 5) void caps_mfma(
    const float* __restrict__ x,
    const _Float16* __restrict__ wb,
    const float* __restrict__ bias,
    float* __restrict__ out)
{
    // Shared buffer, two lifetimes:
    //  phase 1 (stage + K-loop): xt = [cell(5x5)][i(8)][ci padded 32->40] f16, 16000 B
    //  phase 2 (routing): scxh = [wave(4)][i(8)][ca padded 128->136] f16, 8704 B
    __shared__ __align__(16) unsigned char smem[16000];
    _Float16* xt = (_Float16*)smem;
    _Float16* scxh = (_Float16*)smem;

    const int tid = threadIdx.x;
    const int tile = blockIdx.x;            // 0..195 : 14x14 tiles of 4x4 pixels
    const int tu = tile / 14, tv = tile - tu * 14;
    const int u0 = tu * 4, v0 = tv * 4;
    const int rh = blockIdx.y >> 1;         // p & 1
    const int rw = blockIdx.y & 1;          // q & 1
    const int bp = blockIdx.z;              // b'
    const _Float16* wsrc = wb + ((long)blockIdx.y << 14);   // parity slice, 16 KB

    // ---- stage x: fp32 -> f16 tile [ri(5)][rj(5)][i(8)][ci], zero-filled OOB ----
    #pragma unroll
    for (int it = 0; it < 4; ++it) {
        int idx = tid + (it << 8);
        if (idx < 800) {
            int cell = idx >> 5;            // 0..24
            int r = idx & 31;
            int i = r >> 2;
            int ci0 = (r & 3) << 3;
            int ri = cell / 5, rj = cell - ri * 5;
            int gi = u0 + rh - 1 + ri;
            int gj = v0 + rw - 1 + rj;
            float tmp[8] = {0.f, 0.f, 0.f, 0.f, 0.f, 0.f, 0.f, 0.f};
            if ((unsigned)gi < 56u && (unsigned)gj < 56u) {
                const float* src = x + (((i & 3) * 56 + gi) * 56 + gj) * 256
                                     + ((bp * 2 + (i >> 2)) << 5) + ci0;
                float4 a0 = *(const float4*)src;
                float4 a1 = *(const float4*)(src + 4);
                tmp[0] = a0.x; tmp[1] = a0.y; tmp[2] = a0.z; tmp[3] = a0.w;
                tmp[4] = a1.x; tmp[5] = a1.y; tmp[6] = a1.z; tmp[7] = a1.w;
            }
            half8 hv;
            #pragma unroll
            for (int j = 0; j < 8; ++j) hv[j] = (_Float16)tmp[j];
            *(half8*)(xt + (cell * 8 + i) * 40 + ci0) = hv;
        }
    }
    __syncthreads();

    const int l = tid & 63;
    const int w = tid >> 6;                 // wave = u-row within tile
    const int col = l & 31, h = l >> 5;
    const int invA = (l & 31) * 40 + (h << 3);

    // ---- MFMA K-loop, TWO passes of 2 n-tiles: acc is 32 AGPR (not 64). ----
    // After each pass, pack f32 acc -> f16 pairs along j (= pixl*4+il):
    // pf[t][m] = (votes[j=2m], votes[j=2m+1]) at ca = 32t+col.
    h2 pf[4][8];
    #pragma unroll
    for (int half = 0; half < 2; ++half) {
        floatx16 acc0, acc1;
        #pragma unroll
        for (int j = 0; j < 16; ++j) { acc0[j] = 0.f; acc1[j] = 0.f; }
        const int tb = half << 1;
        #pragma unroll
        for (int s = 0; s < 8; ++s) {
            const int tkh = s >> 2;
            const int tkw = (s >> 1) & 1;
            const int row = w + 1 - tkh;
            int aoff = (row * 5 + 1 - tkw) * 320 + ((s & 1) << 4) + invA;
            // SPILL FIX (R14): make the A-frag address opaque so the
            // compiler cannot CSE/hoist the 8 identical xt loads across the
            // two halves (R13: that hoisting (+32 VGPR) caused the spill).
            asm("" : "+v"(aoff));
            half8 af = *(const half8*)(xt + aoff);
            half8 bf0 = *(const half8*)(wsrc + (((s * 4 + tb) * 64 + l) << 3));
            half8 bf1 = *(const half8*)(wsrc + (((s * 4 + tb + 1) * 64 + l) << 3));
            acc0 = __builtin_amdgcn_mfma_f32_32x32x16_f16(af, bf0, acc0, 0, 0, 0);
            acc1 = __builtin_amdgcn_mfma_f32_32x32x16_f16(af, bf1, acc1, 0, 0, 0);
        }
        #pragma unroll
        for (int m = 0; m < 8; ++m) {
            pf[tb][m]     = pkrtz(acc0[2 * m], acc0[2 * m + 1]);
            pf[tb + 1][m] = pkrtz(acc1[2 * m], acc1[2 * m + 1]);
        }
        // keep half-2's loads from being software-pipelined into half-1
        // (would extend acc/af liveness across the packing)
        __builtin_amdgcn_sched_barrier(0);
    }

    // xt is dead; scxh aliases it. All waves must pass here before writing.
    __syncthreads();

    // ---- routing: lane = (c = l>>3, i = l&7); a(16) in-register as h2[8] ----
    _Float16* scb = scxh + w * (8 * 136);   // wave-local after the barrier
    const int cI = l >> 3;
    const int iI = l & 7;

    // bias as packed f16 pairs, loaded once (8 distinct addrs/wave -> L1)
    h2 bq2[8];
    {
        const float* bpt = bias + (cI << 4);
        float4 b0 = *(const float4*)bpt;
        float4 b1 = *(const float4*)(bpt + 4);
        float4 b2 = *(const float4*)(bpt + 8);
        float4 b3 = *(const float4*)(bpt + 12);
        bq2[0] = pkrtz(b0.x, b0.y); bq2[1] = pkrtz(b0.z, b0.w);
        bq2[2] = pkrtz(b1.x, b1.y); bq2[3] = pkrtz(b1.z, b1.w);
        bq2[4] = pkrtz(b2.x, b2.y); bq2[5] = pkrtz(b2.z, b2.w);
        bq2[6] = pkrtz(b3.x, b3.y); bq2[7] = pkrtz(b3.z, b3.w);
    }
    const h2 c0125 = pkrtz(0.125f, 0.125f);

    // ---- ILP-2 routing: pair-groups {0,2} then {1,3} as two jammed streams.
    #pragma unroll
    for (int pg = 0; pg < 2; ++pg) {
        h2 va2[2][8];
        #pragma unroll
        for (int sx = 0; sx < 2; ++sx) {
            const int pixl = pg + 2 * sx;   // group 0: pixl 0,2; group 1: 1,3
            // transpose: packed f16 votes -> scxh[i][ca] (row stride 136)
            #pragma unroll
            for (int t = 0; t < 4; ++t)
                #pragma unroll
                for (int il = 0; il < 4; ++il) {
                    h2 pp = pf[t][(pixl << 1) + (il >> 1)];
                    _Float16 v = (il & 1) ? pp.y : pp.x;
                    scb[((h << 2) + il) * 136 + t * 32 + col] = v;
                }
            // read my (c,i) row: 2x ds_read_b128 -> va2 directly.
            // Stream B reuses stream A's rows: per-wave in-order DS makes
            // the write-after-read safe without a barrier.
            const _Float16* rbh = scb + iI * 136 + (cI << 4);
            *(half8*)&va2[sx][0] = *(const half8*)(rbh);
            *(half8*)&va2[sx][4] = *(const half8*)(rbh + 8);
        }

        h2 pre2[2][8];
        float lg[2];

        // ---- round 0: route = 1/8 (both streams jammed) ----
        #pragma unroll
        for (int j = 0; j < 8; ++j)
            #pragma unroll
            for (int s = 0; s < 2; ++s) {
                h2 s2 = sum_i8_h2(va2[s][j]);
                pre2[s][j] = s2 * c0125 + bq2[j];     // v_pk_fma_f16
            }
        #pragma unroll
        for (int s = 0; s < 2; ++s) {
            float n0 = fdot2(pre2[s][0], pre2[s][0], 0.f);
            float n1 = fdot2(pre2[s][1], pre2[s][1], 0.f);
            float n2 = fdot2(pre2[s][2], pre2[s][2], 0.f);
            float n3 = fdot2(pre2[s][3], pre2[s][3], 0.f);
            n0 = fdot2(pre2[s][4], pre2[s][4], n0);
            n1 = fdot2(pre2[s][5], pre2[s][5], n1);
            n2 = fdot2(pre2[s][6], pre2[s][6], n2);
            n3 = fdot2(pre2[s][7], pre2[s][7], n3);
            float nq = (n0 + n1) + (n2 + n3);
            float sc = nq * __builtin_amdgcn_rcpf(1.f + nq)
                          * __builtin_amdgcn_rsqf(nq + CEPS);
            h2 sc2 = pkrtz(sc, sc);
            #pragma unroll
            for (int j = 0; j < 8; ++j) pre2[s][j] *= sc2;   // pre2 = act
            float d0 = fdot2(va2[s][0], pre2[s][0], 0.f);
            float d1 = fdot2(va2[s][1], pre2[s][1], 0.f);
            float d2 = fdot2(va2[s][2], pre2[s][2], 0.f);
            float d3 = fdot2(va2[s][3], pre2[s][3], 0.f);
            d0 = fdot2(va2[s][4], pre2[s][4], d0);
            d1 = fdot2(va2[s][5], pre2[s][5], d1);
            d2 = fdot2(va2[s][6], pre2[s][6], d2);
            d3 = fdot2(va2[s][7], pre2[s][7], d3);
            lg[s] = (d0 + d1) + (d2 + d3);            // per-(i,c), fp32
        }

        // ---- rounds 1,2 (both streams jammed) ----
        #pragma unroll
        for (int r = 1; r < 3; ++r) {
            // softmax over c (lane bits 3..5); fp32; two independent chains
            float e0 = __expf(lg[0]);
            float e1 = __expf(lg[1]);
            float ss0 = dpp_add<0x128>(e0);           // ror8 == xor8 (in-row)
            float ss1 = dpp_add<0x128>(e1);
            ss0 += __int_as_float(__builtin_amdgcn_ds_swizzle(
                       __float_as_int(ss0), 0x401F)); // xor16
            ss1 += __int_as_float(__builtin_amdgcn_ds_swizzle(
                       __float_as_int(ss1), 0x401F));
            ss0 += __shfl_xor(ss0, 32);
            ss1 += __shfl_xor(ss1, 32);
            h2 rt2[2];
            rt2[0] = pkrtz(e0 * __builtin_amdgcn_rcpf(ss0),
                           e0 * __builtin_amdgcn_rcpf(ss0));
            rt2[1] = pkrtz(e1 * __builtin_amdgcn_rcpf(ss1),
                           e1 * __builtin_amdgcn_rcpf(ss1));
            #pragma unroll
            for (int j = 0; j < 8; ++j)
                #pragma unroll
                for (int s = 0; s < 2; ++s) {
                    h2 p = sum_i8_h2(rt2[s] * va2[s][j]);
                    pre2[s][j] = p + bq2[j];          // v_pk_add_f16
                }
            #pragma unroll
            for (int s = 0; s < 2; ++s) {
                float n0 = fdot2(pre2[s][0], pre2[s][0], 0.f);
                float n1 = fdot2(pre2[s][1], pre2[s][1], 0.f);
                float n2 = fdot2(pre2[s][2], pre2[s][2], 0.f);
                float n3 = fdot2(pre2[s][3], pre2[s][3], 0.f);
                n0 = fdot2(pre2[s][4], pre2[s][4], n0);
                n1 = fdot2(pre2[s][5], pre2[s][5], n1);
                n2 = fdot2(pre2[s][6], pre2[s][6], n2);
                n3 = fdot2(pre2[s][7], pre2[s][7], n3);
                float nq = (n0 + n1) + (n2 + n3);
                float sc = nq * __builtin_amdgcn_rcpf(1.f + nq)
                              * __builtin_amdgcn_rsqf(nq + CEPS);
                h2 sc2 = pkrtz(sc, sc);
                #pragma unroll
                for (int j = 0; j < 8; ++j) pre2[s][j] *= sc2;   // act
                if (r < 2) {
                    float d0 = fdot2(va2[s][0], pre2[s][0], lg[s]);
                    float d1 = fdot2(va2[s][1], pre2[s][1], 0.f);
                    float d2 = fdot2(va2[s][2], pre2[s][2], 0.f);
                    float d3 = fdot2(va2[s][3], pre2[s][3], 0.f);
                    d0 = fdot2(va2[s][4], pre2[s][4], d0);
                    d1 = fdot2(va2[s][5], pre2[s][5], d1);
                    d2 = fdot2(va2[s][6], pre2[s][6], d2);
                    d3 = fdot2(va2[s][7], pre2[s][7], d3);
                    lg[s] = (d0 + d1) + (d2 + d3);
                }
            }
        }

        // ---- store: lanes i<4 write one float4 quad per stream ----
        if (iI < 4) {
            #pragma unroll
            for (int sx = 0; sx < 2; ++sx) {
                const int pixl = pg + 2 * sx;
                // quad q=iI covers pairs j0=2(iI&1)+4((iI>>1)&1), j0+1
                h2 h0 = hsel((iI & 2) != 0, pre2[sx][4], pre2[sx][0]);
                h2 h1 = hsel((iI & 2) != 0, pre2[sx][5], pre2[sx][1]);
                h2 h2_ = hsel((iI & 2) != 0, pre2[sx][6], pre2[sx][2]);
                h2 h3 = hsel((iI & 2) != 0, pre2[sx][7], pre2[sx][3]);
                h2 p0 = hsel((iI & 1) != 0, h2_, h0);
                h2 p1 = hsel((iI & 1) != 0, h3, h1);
                float4 o4 = make_float4((float)p0.x, (float)p0.y,
                                        (float)p1.x, (float)p1.y);
                const int p = ((u0 + w) << 1) + rh;
                const int q = ((v0 + pixl) << 1) + rw;
                *(float4*)(out + (((bp * 112 + p) * 112 + q) << 7)
                           + cI * 16 + iI * 4) = o4;
            }
        }
    }
}

extern "C" void kernel_launch(void* const* d_in, const int* in_sizes, int n_in,
                              void* d_out, int out_size, void* d_ws, size_t ws_size,
                              hipStream_t stream) {
    const float* x  = (const float*)d_in[0];
    const float* Wt = (const float*)d_in[1];
    const float* b  = (const float*)d_in[2];
    float* out = (float*)d_out;
    _Float16* wb = (_Float16*)d_ws;          // 4 parities x 16384 f16 = 64 KB

    prep_w<<<32, 256, 0, stream>>>(Wt, wb);
    dim3 grid(196, 4, 4);    // 14x14 4x4-pixel tiles, 4 parity classes, 4 b'
    caps_mfma<<<grid, 256, 0, stream>>>(x, wb, b, out);
}

// Round 7
// 102.215 us; speedup vs baseline: 1.5154x; 1.1674x over previous
//
#include <hip/hip_runtime.h>
#include <math.h>

#define CEPS 1e-9f

typedef _Float16 half8 __attribute__((ext_vector_type(8)));
typedef _Float16 h2 __attribute__((ext_vector_type(2)));
typedef __fp16 fp16x2 __attribute__((ext_vector_type(2)));
typedef float floatx16 __attribute__((ext_vector_type(16)));

// x  : [4,56,56,8,32] fp32    W: [4,4,128,32] fp32    bias: [128] fp32
// out: [4,112,112,128] fp32 act
//
// R19: routing re-layout, lane=(pixel,c,e). History:
//  R12: 75us (256,4) latency-bound. R13/14/16: all (256,6) tries spilled.
//  R15: (256,5) spill-free 61.4us. R17: f16 scx trims. R18: ILP-2 routing,
//       60.6us -- VALU busy-time pinned at ~37us across R15/17/18 =>
//       ISSUE-bound: only deleting instructions helps now.
//  Old layout lane=(c,i) replicated pre/nq/act/softmax 8x across i-lanes and
//  paid a 6-instr DPP butterfly per i-sum (576 instr/lane) + ds_bpermute in
//  softmax. New layout: transpose ALL 4 pixels to LDS [pl][i][ca] (32768 B
//  exactly -> still 5 blocks/CU), lane owns (pl, c, e)=8 atoms, all 8 i in
//  registers (8x ds_read_b128 = 32 h2):
//   - i-sum = local pk_add tree (bit-identical pairwise association)
//   - squash computed once (not 8x); nq needs one xor1 DPP (e-partner)
//   - softmax over c = lane bits 1..3 -> xor2/xor4/xor8 ALL-DPP (quad_perm,
//     row_half_mirror, ror8); no ds_swizzle, NO ds_bpermute
//   - all 64 lanes store (no divergence)
//  Routing ~1250 -> ~620 instr/lane. K-phase untouched (R14 laundering kept).

template<int CTRL>
__device__ __forceinline__ float dpp_add(float v) {
    return v + __int_as_float(__builtin_amdgcn_update_dpp(
        0, __float_as_int(v), CTRL, 0xF, 0xF, false));
}
__device__ __forceinline__ h2 pkrtz(float a, float b) {
    return __builtin_bit_cast(h2, __builtin_amdgcn_cvt_pkrtz(a, b));
}
__device__ __forceinline__ float fdot2(h2 a, h2 b, float c) {
    return __builtin_amdgcn_fdot2(__builtin_bit_cast(fp16x2, a),
                                  __builtin_bit_cast(fp16x2, b), c, false);
}

// B[k][n] fragment table: idx = ((parity*8 + s)*4 + t)*64 + l -> 8 f16
__global__ __launch_bounds__(256) void prep_w(const float* __restrict__ Wt,
                                              _Float16* __restrict__ wb) {
    int idx = blockIdx.x * 256 + threadIdx.x;    // [0, 8192)
    int parity = idx >> 11;
    int s = (idx >> 8) & 7;
    int t = (idx >> 6) & 3;
    int l = idx & 63;
    int rh = parity >> 1, rw = parity & 1;
    int n = t * 32 + (l & 31);
    int h = l >> 5;
    int ci0 = ((s & 1) << 4) + (h << 3);
    int kh = ((s >> 2) << 1) + 1 - rh;
    int kw = (((s >> 1) & 1) << 1) + 1 - rw;
    const float* src = Wt + (((kh * 4 + kw) * 128 + n) << 5) + ci0;
    float4 w0 = *(const float4*)src;
    float4 w1 = *(const float4*)(src + 4);
    half8 hv;
    hv[0] = (_Float16)w0.x; hv[1] = (_Float16)w0.y;
    hv[2] = (_Float16)w0.z; hv[3] = (_Float16)w0.w;
    hv[4] = (_Float16)w1.x; hv[5] = (_Float16)w1.y;
    hv[6] = (_Float16)w1.z; hv[7] = (_Float16)w1.w;
    *(half8*)(wb + ((long)idx << 3)) = hv;
}

__global__ __launch_bounds__(256, 5) void caps_mfma(
    const float* __restrict__ x,
    const _Float16* __restrict__ wb,
    const float* __restrict__ bias,
    float* __restrict__ out)
{
    // Shared buffer, two lifetimes:
    //  phase 1: xt = [cell(5x5)][i(8)][ci padded 32->40] f16, 16000 B
    //  phase 2: scxh = [wave(4)][pl(4)][i(8)][ca(128)] f16, 32768 B EXACTLY
    //           (163840/32768 = 5 blocks/CU, matching the (256,5) reg cap)
    __shared__ __align__(16) unsigned char smem[32768];
    _Float16* xt = (_Float16*)smem;
    _Float16* scxh = (_Float16*)smem;

    const int tid = threadIdx.x;
    const int tile = blockIdx.x;            // 0..195 : 14x14 tiles of 4x4 pixels
    const int tu = tile / 14, tv = tile - tu * 14;
    const int u0 = tu * 4, v0 = tv * 4;
    const int rh = blockIdx.y >> 1;         // p & 1
    const int rw = blockIdx.y & 1;          // q & 1
    const int bp = blockIdx.z;              // b'
    const _Float16* wsrc = wb + ((long)blockIdx.y << 14);   // parity slice, 16 KB

    // ---- stage x: fp32 -> f16 tile [ri(5)][rj(5)][i(8)][ci], zero-filled OOB ----
    #pragma unroll
    for (int it = 0; it < 4; ++it) {
        int idx = tid + (it << 8);
        if (idx < 800) {
            int cell = idx >> 5;            // 0..24
            int r = idx & 31;
            int i = r >> 2;
            int ci0 = (r & 3) << 3;
            int ri = cell / 5, rj = cell - ri * 5;
            int gi = u0 + rh - 1 + ri;
            int gj = v0 + rw - 1 + rj;
            float tmp[8] = {0.f, 0.f, 0.f, 0.f, 0.f, 0.f, 0.f, 0.f};
            if ((unsigned)gi < 56u && (unsigned)gj < 56u) {
                const float* src = x + (((i & 3) * 56 + gi) * 56 + gj) * 256
                                     + ((bp * 2 + (i >> 2)) << 5) + ci0;
                float4 a0 = *(const float4*)src;
                float4 a1 = *(const float4*)(src + 4);
                tmp[0] = a0.x; tmp[1] = a0.y; tmp[2] = a0.z; tmp[3] = a0.w;
                tmp[4] = a1.x; tmp[5] = a1.y; tmp[6] = a1.z; tmp[7] = a1.w;
            }
            half8 hv;
            #pragma unroll
            for (int j = 0; j < 8; ++j) hv[j] = (_Float16)tmp[j];
            *(half8*)(xt + (cell * 8 + i) * 40 + ci0) = hv;
        }
    }
    __syncthreads();

    const int l = tid & 63;
    const int w = tid >> 6;                 // wave = u-row within tile
    const int col = l & 31, h = l >> 5;
    const int invA = (l & 31) * 40 + (h << 3);

    // ---- MFMA K-loop, TWO passes of 2 n-tiles: acc is 32 AGPR (not 64). ----
    // pf[t][m] = (votes[j=2m], votes[j=2m+1]) at ca = 32t+col; j = pixl*4+il.
    h2 pf[4][8];
    #pragma unroll
    for (int half = 0; half < 2; ++half) {
        floatx16 acc0, acc1;
        #pragma unroll
        for (int j = 0; j < 16; ++j) { acc0[j] = 0.f; acc1[j] = 0.f; }
        const int tb = half << 1;
        #pragma unroll
        for (int s = 0; s < 8; ++s) {
            const int tkh = s >> 2;
            const int tkw = (s >> 1) & 1;
            const int row = w + 1 - tkh;
            int aoff = (row * 5 + 1 - tkw) * 320 + ((s & 1) << 4) + invA;
            // SPILL FIX (R14): opaque A-frag address prevents cross-half CSE
            // of the 8 identical xt loads (R13: +32 live VGPR -> spill).
            asm("" : "+v"(aoff));
            half8 af = *(const half8*)(xt + aoff);
            half8 bf0 = *(const half8*)(wsrc + (((s * 4 + tb) * 64 + l) << 3));
            half8 bf1 = *(const half8*)(wsrc + (((s * 4 + tb + 1) * 64 + l) << 3));
            acc0 = __builtin_amdgcn_mfma_f32_32x32x16_f16(af, bf0, acc0, 0, 0, 0);
            acc1 = __builtin_amdgcn_mfma_f32_32x32x16_f16(af, bf1, acc1, 0, 0, 0);
        }
        #pragma unroll
        for (int m = 0; m < 8; ++m) {
            pf[tb][m]     = pkrtz(acc0[2 * m], acc0[2 * m + 1]);
            pf[tb + 1][m] = pkrtz(acc1[2 * m], acc1[2 * m + 1]);
        }
        __builtin_amdgcn_sched_barrier(0);
    }

    // xt is dead; scxh aliases it. All waves must pass here before writing.
    __syncthreads();

    // ---- transpose ALL 4 pixels: votes -> scxh[w][pl][i][ca] ----
    // row = pixl*8 + i, i = 4h + il; addr(f16) = w*4096 + (pl*8+i)*128 + ca.
    // Per-lane base covers (h, col); (pl, il, t) are immediate offsets.
    _Float16* wbW = scxh + (w << 12);
    {
        _Float16* wp = wbW + (h << 9) + col;
        #pragma unroll
        for (int t = 0; t < 4; ++t)
            #pragma unroll
            for (int m = 0; m < 8; ++m) {
                h2 pp = pf[t][m];
                const int pixl = m >> 1;
                const int il0 = (2 * m) & 3;
                const int il1 = (2 * m + 1) & 3;
                wp[pixl * 1024 + il0 * 128 + t * 32] = pp[0];
                wp[pixl * 1024 + il1 * 128 + t * 32] = pp[1];
            }
    }
    // wave-local RAW through LDS: in-order DS per wave, no barrier needed.

    // ---- routing: lane = (pl = l>>4, c = (l>>1)&7, e = l&1) ----
    const int e = l & 1;
    const int c = (l >> 1) & 7;
    const int pl = l >> 4;

    // all 8 i-votes for my 8 atoms, in registers: 8x ds_read_b128
    h2 va[8][4];
    {
        const _Float16* rp = wbW + (pl << 10) + (c << 4) + (e << 3);
        #pragma unroll
        for (int i = 0; i < 8; ++i) {
            half8 vv = *(const half8*)(rp + (i << 7));
            va[i][0][0] = vv[0]; va[i][0][1] = vv[1];
            va[i][1][0] = vv[2]; va[i][1][1] = vv[3];
            va[i][2][0] = vv[4]; va[i][2][1] = vv[5];
            va[i][3][0] = vv[6]; va[i][3][1] = vv[7];
        }
    }

    // bias: my 8 atoms of capsule c
    h2 bq[4];
    {
        const float* bpt = bias + (c << 4) + (e << 3);
        float4 b0 = *(const float4*)bpt;
        float4 b1 = *(const float4*)(bpt + 4);
        bq[0] = pkrtz(b0.x, b0.y); bq[1] = pkrtz(b0.z, b0.w);
        bq[2] = pkrtz(b1.x, b1.y); bq[3] = pkrtz(b1.z, b1.w);
    }
    const h2 c0125 = pkrtz(0.125f, 0.125f);

    h2 pre[4];
    float lgv[8];

    // ---- round 0: route = 1/8; i-sum = local pk_add tree (butterfly order) ----
    #pragma unroll
    for (int d = 0; d < 4; ++d) {
        h2 s01 = va[0][d] + va[1][d];
        h2 s23 = va[2][d] + va[3][d];
        h2 s45 = va[4][d] + va[5][d];
        h2 s67 = va[6][d] + va[7][d];
        h2 s = (s01 + s23) + (s45 + s67);
        pre[d] = s * c0125 + bq[d];
    }
    {
        float n = fdot2(pre[0], pre[0], 0.f);
        n = fdot2(pre[1], pre[1], n);
        n = fdot2(pre[2], pre[2], n);
        n = fdot2(pre[3], pre[3], n);
        float nq = dpp_add<0xB1>(n);          // + e-partner -> full 16-atom norm
        float sc = nq * __builtin_amdgcn_rcpf(1.f + nq)
                      * __builtin_amdgcn_rsqf(nq + CEPS);
        h2 sc2 = pkrtz(sc, sc);
        #pragma unroll
        for (int d = 0; d < 4; ++d) pre[d] *= sc2;      // pre = act
    }
    #pragma unroll
    for (int i = 0; i < 8; ++i) {
        float p = fdot2(va[i][0], pre[0], 0.f);
        p = fdot2(va[i][1], pre[1], p);
        p = fdot2(va[i][2], pre[2], p);
        p = fdot2(va[i][3], pre[3], p);
        lgv[i] = dpp_add<0xB1>(p);            // full 16-atom dot, per i
    }

    // ---- rounds 1,2 ----
    #pragma unroll
    for (int r = 1; r < 3; ++r) {
        // softmax over c (lane bits 1..3): xor2 / xor4 / xor8, all DPP.
        // (bits 0..1 uniform before the mirror stage -> l^7 == l^4)
        h2 rt2[8];
        #pragma unroll
        for (int i = 0; i < 8; ++i) {
            float ee = __expf(lgv[i]);
            float ss = dpp_add<0x4E>(ee);     // quad_perm xor2 : c^1
            ss = dpp_add<0x141>(ss);          // row_half_mirror == xor4 : c^2
            ss = dpp_add<0x128>(ss);          // row ror8 == xor8 : c^4
            float route = ee * __builtin_amdgcn_rcpf(ss);
            rt2[i] = pkrtz(route, route);
        }
        #pragma unroll
        for (int d = 0; d < 4; ++d) {
            h2 p0 = rt2[0] * va[0][d], p1 = rt2[1] * va[1][d];
            h2 p2 = rt2[2] * va[2][d], p3 = rt2[3] * va[3][d];
            h2 p4 = rt2[4] * va[4][d], p5 = rt2[5] * va[5][d];
            h2 p6 = rt2[6] * va[6][d], p7 = rt2[7] * va[7][d];
            h2 s = ((p0 + p1) + (p2 + p3)) + ((p4 + p5) + (p6 + p7));
            pre[d] = s + bq[d];
        }
        {
            float n = fdot2(pre[0], pre[0], 0.f);
            n = fdot2(pre[1], pre[1], n);
            n = fdot2(pre[2], pre[2], n);
            n = fdot2(pre[3], pre[3], n);
            float nq = dpp_add<0xB1>(n);
            float sc = nq * __builtin_amdgcn_rcpf(1.f + nq)
                          * __builtin_amdgcn_rsqf(nq + CEPS);
            h2 sc2 = pkrtz(sc, sc);
            #pragma unroll
            for (int d = 0; d < 4; ++d) pre[d] *= sc2;  // act
        }
        if (r < 2) {
            #pragma unroll
            for (int i = 0; i < 8; ++i) {
                float p = fdot2(va[i][0], pre[0], 0.f);
                p = fdot2(va[i][1], pre[1], p);
                p = fdot2(va[i][2], pre[2], p);
                p = fdot2(va[i][3], pre[3], p);
                lgv[i] += dpp_add<0xB1>(p);
            }
        }
    }

    // ---- store: every lane writes its 8 atoms = 2x float4, coalesced ----
    {
        const int p = ((u0 + w) << 1) + rh;
        const int q = ((v0 + pl) << 1) + rw;
        float* op = out + (((bp * 112 + p) * 112 + q) << 7) + (c << 4) + (e << 3);
        float4 o0 = make_float4((float)pre[0][0], (float)pre[0][1],
                                (float)pre[1][0], (float)pre[1][1]);
        float4 o1 = make_float4((float)pre[2][0], (float)pre[2][1],
                                (float)pre[3][0], (float)pre[3][1]);
        *(float4*)op = o0;
        *(float4*)(op + 4) = o1;
    }
}

extern "C" void kernel_launch(void* const* d_in, const int* in_sizes, int n_in,
                              void* d_out, int out_size, void* d_ws, size_t ws_size,
                              hipStream_t stream) {
    const float* x  = (const float*)d_in[0];
    const float* Wt = (const float*)d_in[1];
    const float* b  = (const float*)d_in[2];
    float* out = (float*)d_out;
    _Float16* wb = (_Float16*)d_ws;          // 4 parities x 16384 f16 = 64 KB

    prep_w<<<32, 256, 0, stream>>>(Wt, wb);
    dim3 grid(196, 4, 4);    // 14x14 4x4-pixel tiles, 4 parity classes, 4 b'
    caps_mfma<<<grid, 256, 0, stream>>>(x, wb, b, out);
}